// Round 11
// baseline (593.050 us; speedup 1.0000x reference)
//
#include <hip/hip_runtime.h>
#include <math.h>

typedef unsigned short ushort_t;
typedef short bf16x8 __attribute__((ext_vector_type(8)));
typedef float f32x4 __attribute__((ext_vector_type(4)));

#define SLABF (512 * 576)     /* floats per (b,t) slab == ushorts per plane */
#define APAD  40              /* K-loop LDS row pad, halves (80 B) */
#define EPAD  72              /* epilogue LDS row pad, halves (144 B) */
#define NXF   (2 * 512 * 16 * 576)   /* elements per xT plane */
#define WELEM (512 * 512)
#define HPLANE (576 * 64)     /* per-head elements of [p][64] plane */

__device__ __forceinline__ float bf2f(ushort_t u) {
    union { unsigned int i; float f; } v;
    v.i = ((unsigned int)u) << 16;
    return v.f;
}
__device__ __forceinline__ ushort_t f2bf(float f) {
    union { float f; unsigned int i; } v;
    v.f = f;
    unsigned int r = v.i + 0x7FFFu + ((v.i >> 16) & 1u);
    return (ushort_t)(r >> 16);
}
__device__ __forceinline__ void split_hl(float x, ushort_t& hi, ushort_t& lo) {
    hi = f2bf(x);
    lo = f2bf(x - bf2f(hi));
}
__device__ __forceinline__ int xcd_swz(int L, int N) {
    return ((N & 7) == 0) ? ((L & 7) * (N >> 3) + (L >> 3)) : L;
}

// ---------------------------------------------------------------------------
// Prep 1: xT hi/lo planes of (x + pos), transposed to [bt][p=576][c=512].
// ---------------------------------------------------------------------------
__global__ __launch_bounds__(256)
void split_xT(const float* __restrict__ x, const float* __restrict__ pos,
              ushort_t* __restrict__ xhi, ushort_t* __restrict__ xlo)
{
    const int bt = blockIdx.z;
    const int b = bt >> 4, t = bt & 15;
    const int pt0 = blockIdx.x * 64;
    const int ct0 = blockIdx.y * 64;
    const int tid = threadIdx.x;

    __shared__ ushort_t Th[64][72], Tl[64][72];

    {
        const int cr = tid >> 2;
        const int pg = (tid & 3) * 16;
        const int c = ct0 + cr;
        const float pv = pos[c * 16 + t];
        const float* src = x + ((size_t)(b * 512 + c) * 16 + t) * 576 + pt0 + pg;
        #pragma unroll
        for (int jj = 0; jj < 4; ++jj) {
            float4 v = *(const float4*)(src + jj * 4);
            v.x += pv; v.y += pv; v.z += pv; v.w += pv;
            ushort_t h, l;
            split_hl(v.x, h, l); Th[pg + jj*4 + 0][cr] = h; Tl[pg + jj*4 + 0][cr] = l;
            split_hl(v.y, h, l); Th[pg + jj*4 + 1][cr] = h; Tl[pg + jj*4 + 1][cr] = l;
            split_hl(v.z, h, l); Th[pg + jj*4 + 2][cr] = h; Tl[pg + jj*4 + 2][cr] = l;
            split_hl(v.w, h, l); Th[pg + jj*4 + 3][cr] = h; Tl[pg + jj*4 + 3][cr] = l;
        }
    }
    __syncthreads();
    {
        const int pr = tid >> 2;
        const int cg = (tid & 3) * 16;
        const size_t obase = (size_t)bt * (576 * 512) + (size_t)(pt0 + pr) * 512 + ct0 + cg;
        #pragma unroll
        for (int m = 0; m < 2; ++m) {
            *(uint4*)(xhi + obase + m * 8) = *(const uint4*)&Th[pr][cg + m * 8];
            *(uint4*)(xlo + obase + m * 8) = *(const uint4*)&Tl[pr][cg + m * 8];
        }
    }
}

// ---------------------------------------------------------------------------
// Prep 2: weight hi/lo planes.
// ---------------------------------------------------------------------------
__global__ __launch_bounds__(256)
void split_w(const float* __restrict__ w0, const float* __restrict__ w1,
             const float* __restrict__ w2, const float* __restrict__ w3,
             ushort_t* __restrict__ wsp)
{
    const int m = blockIdx.y;
    const float* W = (m == 0) ? w0 : (m == 1) ? w1 : (m == 2) ? w2 : w3;
    ushort_t* hi = wsp + (size_t)m * 2 * WELEM;
    ushort_t* lo = hi + WELEM;
    const int idx = blockIdx.x * 256 + threadIdx.x;
    float4 v = ((const float4*)W)[idx];
    ushort4 h, l;
    split_hl(v.x, h.x, l.x);
    split_hl(v.y, h.y, l.y);
    split_hl(v.z, h.z, l.z);
    split_hl(v.w, h.w, l.w);
    ((ushort4*)hi)[idx] = h;
    ((ushort4*)lo)[idx] = l;
}

// ---------------------------------------------------------------------------
// QKV projection, MFMA hi/lo 3-pass, 256o x 64p tile, BK=32, 4 waves.
// T14: register-staged prefetch of next K-step overlaps MFMA.
// Epilogue: per-wave LDS transpose tiles -> full-line uint4 global stores.
// Outputs: Q planes [h][p][64] (pre-scaled 0.125), K planes [h][kv][64],
//          V planes [h][d][576]; all hi/lo.
// ---------------------------------------------------------------------------
__global__ __launch_bounds__(256)
void proj_qkv_mfma(const ushort_t* __restrict__ xhi, const ushort_t* __restrict__ xlo,
                   const ushort_t* __restrict__ wsp,
                   const float* __restrict__ bq, const float* __restrict__ bk,
                   const float* __restrict__ bv,
                   float* __restrict__ qs, float* __restrict__ ks, float* __restrict__ vs,
                   int bt_base, int nbt)
{
    const int w = xcd_swz(blockIdx.x, nbt * 54);
    const int btl = w / 54;
    int r = w - btl * 54;
    const int mode = r / 18; r -= mode * 18;
    const int ot = r / 9;
    const int pt = r - ot * 9;
    const int bt = bt_base + btl;

    const ushort_t* Whi = wsp + (size_t)mode * (2 * WELEM);
    const ushort_t* Wlo = Whi + WELEM;
    const float* bias = (mode == 0) ? bq : (mode == 1) ? bk : bv;
    float* outf = ((mode == 0) ? qs : (mode == 1) ? ks : vs) + (size_t)btl * SLABF;
    ushort_t* ohi = (ushort_t*)outf;
    ushort_t* olo = ohi + SLABF;

    const int o0 = ot * 256;
    const int p0 = pt * 64;
    const int tid = threadIdx.x;
    const int wid = tid >> 6;
    const int lane = tid & 63;
    const int lr = lane & 15;
    const int lk = lane >> 4;

    __shared__ __align__(16) ushort_t lds[25600];   // 51200 B, reused by epilogue
    ushort_t* Wh = lds;                 // 256*APAD
    ushort_t* Wl = lds + 10240;
    ushort_t* Xh = lds + 20480;         // 64*APAD
    ushort_t* Xl = lds + 23040;

    f32x4 acc[4][4];
    #pragma unroll
    for (int i = 0; i < 4; ++i)
        #pragma unroll
        for (int j = 0; j < 4; ++j) { f32x4 zz = {0.f,0.f,0.f,0.f}; acc[i][j] = zz; }

    const int brow = tid >> 2, boff = (tid & 3) * 8;
    const ushort_t* xbh = xhi + (size_t)bt * (576 * 512);
    const ushort_t* xbl = xlo + (size_t)bt * (576 * 512);

    uint4 wr_h[4], wr_l[4], xr_h, xr_l;
    // prologue: load step 0
    #pragma unroll
    for (int k = 0; k < 4; ++k) {
        const int ci = tid + k * 256;
        const int row = ci >> 2, off = (ci & 3) * 8;
        const size_t g = (size_t)(o0 + row) * 512 + off;
        wr_h[k] = *(const uint4*)(Whi + g);
        wr_l[k] = *(const uint4*)(Wlo + g);
    }
    {
        const size_t g = (size_t)(p0 + brow) * 512 + boff;
        xr_h = *(const uint4*)(xbh + g);
        xr_l = *(const uint4*)(xbl + g);
    }

    for (int c0 = 0; c0 < 512; c0 += 32) {
        __syncthreads();   // previous compute done reading LDS
        #pragma unroll
        for (int k = 0; k < 4; ++k) {
            const int ci = tid + k * 256;
            const int row = ci >> 2, off = (ci & 3) * 8;
            *(uint4*)(Wh + row * APAD + off) = wr_h[k];
            *(uint4*)(Wl + row * APAD + off) = wr_l[k];
        }
        *(uint4*)(Xh + brow * APAD + boff) = xr_h;
        *(uint4*)(Xl + brow * APAD + boff) = xr_l;
        __syncthreads();
        if (c0 + 32 < 512) {   // issue next step's loads; latency hides under MFMA
            #pragma unroll
            for (int k = 0; k < 4; ++k) {
                const int ci = tid + k * 256;
                const int row = ci >> 2, off = (ci & 3) * 8;
                const size_t g = (size_t)(o0 + row) * 512 + c0 + 32 + off;
                wr_h[k] = *(const uint4*)(Whi + g);
                wr_l[k] = *(const uint4*)(Wlo + g);
            }
            const size_t g = (size_t)(p0 + brow) * 512 + c0 + 32 + boff;
            xr_h = *(const uint4*)(xbh + g);
            xr_l = *(const uint4*)(xbl + g);
        }

        bf16x8 ah[4], al[4];
        #pragma unroll
        for (int fo = 0; fo < 4; ++fo) {
            ah[fo] = *(const bf16x8*)(Wh + (wid * 64 + fo * 16 + lr) * APAD + lk * 8);
            al[fo] = *(const bf16x8*)(Wl + (wid * 64 + fo * 16 + lr) * APAD + lk * 8);
        }
        #pragma unroll
        for (int fp = 0; fp < 4; ++fp) {
            bf16x8 bh = *(const bf16x8*)(Xh + (fp * 16 + lr) * APAD + lk * 8);
            bf16x8 bl = *(const bf16x8*)(Xl + (fp * 16 + lr) * APAD + lk * 8);
            #pragma unroll
            for (int fo = 0; fo < 4; ++fo) {
                acc[fo][fp] = __builtin_amdgcn_mfma_f32_16x16x32_bf16(ah[fo], bh, acc[fo][fp], 0, 0, 0);
                acc[fo][fp] = __builtin_amdgcn_mfma_f32_16x16x32_bf16(al[fo], bh, acc[fo][fp], 0, 0, 0);
                acc[fo][fp] = __builtin_amdgcn_mfma_f32_16x16x32_bf16(ah[fo], bl, acc[fo][fp], 0, 0, 0);
            }
        }
    }

    // ---- epilogue: per-wave LDS tile [64][EPAD], 2 passes (hi, lo) ----
    __syncthreads();   // all waves done with K-loop LDS
    ushort_t* Ew = lds + wid * (64 * EPAD);
    const int head = (o0 >> 6) + wid;

    #pragma unroll
    for (int pass = 0; pass < 2; ++pass) {
        if (mode != 2) {
            // Q/K tile rows = p', cols = d' (vector staging: 4 regs = 4 consec d')
            #pragma unroll
            for (int fo = 0; fo < 4; ++fo)
                #pragma unroll
                for (int fp = 0; fp < 4; ++fp) {
                    ushort4 s;
                    #pragma unroll
                    for (int reg = 0; reg < 4; ++reg) {
                        const int o = o0 + wid * 64 + fo * 16 + lk * 4 + reg;
                        float v = acc[fo][fp][reg] + bias[o];
                        if (mode == 0) v *= 0.125f;
                        ushort_t hi = f2bf(v);
                        ((ushort_t*)&s)[reg] = pass ? f2bf(v - bf2f(hi)) : hi;
                    }
                    *(ushort4*)&Ew[(fp * 16 + lr) * EPAD + fo * 16 + lk * 4] = s;
                }
        } else {
            // V tile rows = d', cols = p' (scalar staging, conflict-free cols)
            #pragma unroll
            for (int fo = 0; fo < 4; ++fo)
                #pragma unroll
                for (int fp = 0; fp < 4; ++fp)
                    #pragma unroll
                    for (int reg = 0; reg < 4; ++reg) {
                        const int o = o0 + wid * 64 + fo * 16 + lk * 4 + reg;
                        float v = acc[fo][fp][reg] + bias[o];
                        ushort_t hi = f2bf(v);
                        Ew[(fo * 16 + lk * 4 + reg) * EPAD + fp * 16 + lr] =
                            pass ? f2bf(v - bf2f(hi)) : hi;
                    }
        }
        asm volatile("s_waitcnt lgkmcnt(0)" ::: "memory");
        __builtin_amdgcn_sched_barrier(0);

        ushort_t* dst = pass ? olo : ohi;
        #pragma unroll
        for (int it = 0; it < 8; ++it) {
            const int row = it * 8 + (lane >> 3);
            const int off = (lane & 7) * 8;
            uint4 v = *(const uint4*)&Ew[row * EPAD + off];
            if (mode != 2)
                *(uint4*)(dst + (size_t)head * HPLANE + (size_t)(p0 + row) * 64 + off) = v;
            else
                *(uint4*)(dst + (size_t)(o0 + wid * 64 + row) * 576 + p0 + off) = v;
        }
        asm volatile("s_waitcnt lgkmcnt(0)" ::: "memory");   // reads retire before pass-1 overwrite
        __builtin_amdgcn_sched_barrier(0);
    }
}

// ---------------------------------------------------------------------------
// Attention via MFMA, hi/lo 3-pass — core loop HW-verified (rounds 7-9).
// AO write-back staged through Qh/Ql (wave-private rows) then full-line
// coalesced uint4 stores.
// ---------------------------------------------------------------------------
__global__ __launch_bounds__(256)
void attn_mfma(float* __restrict__ qs, const float* __restrict__ ks,
               const float* __restrict__ vs, int nbt)
{
    const int w9 = xcd_swz(blockIdx.x, nbt * 72);
    const int pair = w9 / 9;
    const int qt = w9 - pair * 9;
    const int btl = pair >> 3;
    const int h = pair & 7;

    const int tid = threadIdx.x;
    const int wid = tid >> 6;
    const int lane = tid & 63;
    const int lr = lane & 15;
    const int lk = lane >> 4;

    const size_t slab = (size_t)btl * SLABF;
    ushort_t* Qhi_g = (ushort_t*)(qs + slab) + (size_t)h * HPLANE;
    ushort_t* Qlo_g = (ushort_t*)(qs + slab) + SLABF + (size_t)h * HPLANE;
    const ushort_t* kbase = (const ushort_t*)(ks + slab);
    const ushort_t* Khi_g = kbase + (size_t)h * HPLANE;
    const ushort_t* Klo_g = kbase + SLABF + (size_t)h * HPLANE;
    const ushort_t* vbase = (const ushort_t*)(vs + slab);
    const ushort_t* Vhi_g = vbase + (size_t)h * HPLANE;
    const ushort_t* Vlo_g = vbase + SLABF + (size_t)h * HPLANE;

    __shared__ ushort_t Kh[32][72], Kl[32][72];
    __shared__ ushort_t Vh[64][40], Vl[64][40];
    __shared__ ushort_t Qh[64][72], Ql[64][72];
    __shared__ ushort_t Ph[4][16][40], Pl[4][16][40];
    __shared__ float Lrow[4][16];

    #pragma unroll
    for (int k = 0; k < 2; ++k) {
        const int ci = tid + k * 256;
        const int row = ci >> 3;
        const int off = (ci & 7) * 8;
        const size_t g = (size_t)(qt * 64 + row) * 64 + off;
        *(uint4*)&Qh[row][off] = *(const uint4*)(Qhi_g + g);
        *(uint4*)&Ql[row][off] = *(const uint4*)(Qlo_g + g);
    }

    const int skv = tid >> 3, sd = (tid & 7) * 8;
    const int svd = tid >> 2, skb = (tid & 3) * 8;
    uint4 kh_r, kl_r, vh_r, vl_r;

    {
        const size_t ko = (size_t)skv * 64 + sd;
        kh_r = *(const uint4*)(Khi_g + ko);
        kl_r = *(const uint4*)(Klo_g + ko);
        const size_t vo = (size_t)svd * 576 + skb;
        vh_r = *(const uint4*)(Vhi_g + vo);
        vl_r = *(const uint4*)(Vlo_g + vo);
        *(uint4*)&Kh[skv][sd] = kh_r; *(uint4*)&Kl[skv][sd] = kl_r;
        *(uint4*)&Vh[svd][skb] = vh_r; *(uint4*)&Vl[svd][skb] = vl_r;
    }
    __syncthreads();

    bf16x8 qh0 = *(const bf16x8*)&Qh[wid * 16 + lr][lk * 8];
    bf16x8 ql0 = *(const bf16x8*)&Ql[wid * 16 + lr][lk * 8];
    bf16x8 qh1 = *(const bf16x8*)&Qh[wid * 16 + lr][32 + lk * 8];
    bf16x8 ql1 = *(const bf16x8*)&Ql[wid * 16 + lr][32 + lk * 8];

    f32x4 o[4];
    #pragma unroll
    for (int nf = 0; nf < 4; ++nf) { f32x4 zz = {0.f,0.f,0.f,0.f}; o[nf] = zz; }
    float lsum = 0.f;

    const int NT = 18;
    for (int tt = 0; tt < NT; ++tt) {
        if (tt + 1 < NT) {
            const size_t ko = (size_t)((tt + 1) * 32 + skv) * 64 + sd;
            kh_r = *(const uint4*)(Khi_g + ko);
            kl_r = *(const uint4*)(Klo_g + ko);
            const size_t vo = (size_t)svd * 576 + (tt + 1) * 32 + skb;
            vh_r = *(const uint4*)(Vhi_g + vo);
            vl_r = *(const uint4*)(Vlo_g + vo);
        }

        f32x4 s0 = {0.f,0.f,0.f,0.f}, s1 = {0.f,0.f,0.f,0.f};
        #pragma unroll
        for (int ks2 = 0; ks2 < 2; ++ks2) {
            const int dof = ks2 * 32 + lk * 8;
            bf16x8 qh = ks2 ? qh1 : qh0;
            bf16x8 ql = ks2 ? ql1 : ql0;
            bf16x8 k0h = *(const bf16x8*)&Kh[lr][dof];
            bf16x8 k0l = *(const bf16x8*)&Kl[lr][dof];
            bf16x8 k1h = *(const bf16x8*)&Kh[16 + lr][dof];
            bf16x8 k1l = *(const bf16x8*)&Kl[16 + lr][dof];
            s0 = __builtin_amdgcn_mfma_f32_16x16x32_bf16(k0h, qh, s0, 0, 0, 0);
            s0 = __builtin_amdgcn_mfma_f32_16x16x32_bf16(k0l, qh, s0, 0, 0, 0);
            s0 = __builtin_amdgcn_mfma_f32_16x16x32_bf16(k0h, ql, s0, 0, 0, 0);
            s1 = __builtin_amdgcn_mfma_f32_16x16x32_bf16(k1h, qh, s1, 0, 0, 0);
            s1 = __builtin_amdgcn_mfma_f32_16x16x32_bf16(k1l, qh, s1, 0, 0, 0);
            s1 = __builtin_amdgcn_mfma_f32_16x16x32_bf16(k1h, ql, s1, 0, 0, 0);
        }

        #pragma unroll
        for (int f = 0; f < 2; ++f) {
            f32x4 sv = f ? s1 : s0;
            float p0 = __expf(sv[0]);
            float p1 = __expf(sv[1]);
            float p2 = __expf(sv[2]);
            float p3 = __expf(sv[3]);
            lsum += (p0 + p1) + (p2 + p3);
            ushort_t h0, l0, h1, l1, h2, l2, h3, l3;
            split_hl(p0, h0, l0); split_hl(p1, h1, l1);
            split_hl(p2, h2, l2); split_hl(p3, h3, l3);
            uint2 wh, wl;
            wh.x = (unsigned int)h0 | ((unsigned int)h1 << 16);
            wh.y = (unsigned int)h2 | ((unsigned int)h3 << 16);
            wl.x = (unsigned int)l0 | ((unsigned int)l1 << 16);
            wl.y = (unsigned int)l2 | ((unsigned int)l3 << 16);
            *(uint2*)&Ph[wid][lr][f * 16 + lk * 4] = wh;
            *(uint2*)&Pl[wid][lr][f * 16 + lk * 4] = wl;
        }
        asm volatile("s_waitcnt lgkmcnt(0)" ::: "memory");
        __builtin_amdgcn_sched_barrier(0);

        {
            bf16x8 pah = *(const bf16x8*)&Ph[wid][lr][lk * 8];
            bf16x8 pal = *(const bf16x8*)&Pl[wid][lr][lk * 8];
            #pragma unroll
            for (int nf = 0; nf < 4; ++nf) {
                bf16x8 vhf = *(const bf16x8*)&Vh[nf * 16 + lr][lk * 8];
                bf16x8 vlf = *(const bf16x8*)&Vl[nf * 16 + lr][lk * 8];
                o[nf] = __builtin_amdgcn_mfma_f32_16x16x32_bf16(pah, vhf, o[nf], 0, 0, 0);
                o[nf] = __builtin_amdgcn_mfma_f32_16x16x32_bf16(pal, vhf, o[nf], 0, 0, 0);
                o[nf] = __builtin_amdgcn_mfma_f32_16x16x32_bf16(pah, vlf, o[nf], 0, 0, 0);
            }
        }

        __syncthreads();
        if (tt + 1 < NT) {
            *(uint4*)&Kh[skv][sd] = kh_r; *(uint4*)&Kl[skv][sd] = kl_r;
            *(uint4*)&Vh[svd][skb] = vh_r; *(uint4*)&Vl[svd][skb] = vl_r;
            __syncthreads();
        }
    }

    lsum += __shfl_xor(lsum, 16);
    lsum += __shfl_xor(lsum, 32);
    if (lk == 0) Lrow[wid][lr] = lsum;
    asm volatile("s_waitcnt lgkmcnt(0)" ::: "memory");
    __builtin_amdgcn_sched_barrier(0);

    float4 lv = *(float4*)&Lrow[wid][lk * 4];
    const float inv[4] = {1.f / lv.x, 1.f / lv.y, 1.f / lv.z, 1.f / lv.w};

    // ---- AO: stage into wave-private Qh/Ql rows, then coalesced store ----
    const int qrow_l = wid * 16 + lk * 4;
    #pragma unroll
    for (int nf = 0; nf < 4; ++nf)
        #pragma unroll
        for (int reg = 0; reg < 4; ++reg) {
            float v = o[nf][reg] * inv[reg];
            ushort_t hi, lo; split_hl(v, hi, lo);
            Qh[qrow_l + reg][nf * 16 + lr] = hi;
            Ql[qrow_l + reg][nf * 16 + lr] = lo;
        }
    asm volatile("s_waitcnt lgkmcnt(0)" ::: "memory");
    __builtin_amdgcn_sched_barrier(0);
    #pragma unroll
    for (int it = 0; it < 2; ++it) {
        const int rl = wid * 16 + it * 8 + (lane >> 3);
        const int off = (lane & 7) * 8;
        const size_t g = (size_t)(qt * 64 + rl) * 64 + off;
        *(uint4*)(Qhi_g + g) = *(const uint4*)&Qh[rl][off];
        *(uint4*)(Qlo_g + g) = *(const uint4*)&Ql[rl][off];
    }
}

// ---------------------------------------------------------------------------
// Output projection, MFMA hi/lo 3-pass, T14-staged loop, fp32 LDS epilogue
// (2 passes of 32 o-rows) -> full-line float4 stores.
// ---------------------------------------------------------------------------
__global__ __launch_bounds__(256)
void proj_out_mfma(const float* __restrict__ ao, const ushort_t* __restrict__ wsp,
                   const float* __restrict__ bo, float* __restrict__ outb,
                   int bt_base, int nbt)
{
    const int w = xcd_swz(blockIdx.x, nbt * 18);
    const int btl = w / 18;
    int r = w - btl * 18;
    const int ot = r / 9;
    const int pt = r - ot * 9;
    const int bt = bt_base + btl;
    const int b = bt >> 4, t = bt & 15;

    const ushort_t* AOhi = (const ushort_t*)(ao + (size_t)btl * SLABF);
    const ushort_t* AOlo = AOhi + SLABF;
    const ushort_t* Whi = wsp + (size_t)3 * (2 * WELEM);
    const ushort_t* Wlo = Whi + WELEM;

    const int o0 = ot * 256;
    const int p0 = pt * 64;
    const int tid = threadIdx.x;
    const int wid = tid >> 6;
    const int lane = tid & 63;
    const int lr = lane & 15;
    const int lk = lane >> 4;

    __shared__ __align__(16) ushort_t lds[25600];
    ushort_t* Wh = lds;
    ushort_t* Wl = lds + 10240;
    ushort_t* Xh = lds + 20480;
    ushort_t* Xl = lds + 23040;

    f32x4 acc[4][4];
    #pragma unroll
    for (int i = 0; i < 4; ++i)
        #pragma unroll
        for (int j = 0; j < 4; ++j) { f32x4 zz = {0.f,0.f,0.f,0.f}; acc[i][j] = zz; }

    const int brow = tid >> 2, boff = (tid & 3) * 8;

    uint4 wr_h[4], wr_l[4], xr_h, xr_l;
    #pragma unroll
    for (int k = 0; k < 4; ++k) {
        const int ci = tid + k * 256;
        const int row = ci >> 2, off = (ci & 3) * 8;
        const size_t g = (size_t)(o0 + row) * 512 + off;
        wr_h[k] = *(const uint4*)(Whi + g);
        wr_l[k] = *(const uint4*)(Wlo + g);
    }
    {
        const size_t g = (size_t)(p0 + brow) * 64 + boff;   // c0=0: head 0, d off
        xr_h = *(const uint4*)(AOhi + g);
        xr_l = *(const uint4*)(AOlo + g);
    }

    for (int c0 = 0; c0 < 512; c0 += 32) {
        __syncthreads();
        #pragma unroll
        for (int k = 0; k < 4; ++k) {
            const int ci = tid + k * 256;
            const int row = ci >> 2, off = (ci & 3) * 8;
            *(uint4*)(Wh + row * APAD + off) = wr_h[k];
            *(uint4*)(Wl + row * APAD + off) = wr_l[k];
        }
        *(uint4*)(Xh + brow * APAD + boff) = xr_h;
        *(uint4*)(Xl + brow * APAD + boff) = xr_l;
        __syncthreads();
        if (c0 + 32 < 512) {
            const int cn = c0 + 32;
            #pragma unroll
            for (int k = 0; k < 4; ++k) {
                const int ci = tid + k * 256;
                const int row = ci >> 2, off = (ci & 3) * 8;
                const size_t g = (size_t)(o0 + row) * 512 + cn + off;
                wr_h[k] = *(const uint4*)(Whi + g);
                wr_l[k] = *(const uint4*)(Wlo + g);
            }
            const size_t g = (size_t)(cn >> 6) * HPLANE
                           + (size_t)(p0 + brow) * 64 + (cn & 63) + boff;
            xr_h = *(const uint4*)(AOhi + g);
            xr_l = *(const uint4*)(AOlo + g);
        }

        bf16x8 ah[4], al[4];
        #pragma unroll
        for (int fo = 0; fo < 4; ++fo) {
            ah[fo] = *(const bf16x8*)(Wh + (wid * 64 + fo * 16 + lr) * APAD + lk * 8);
            al[fo] = *(const bf16x8*)(Wl + (wid * 64 + fo * 16 + lr) * APAD + lk * 8);
        }
        #pragma unroll
        for (int fp = 0; fp < 4; ++fp) {
            bf16x8 bh = *(const bf16x8*)(Xh + (fp * 16 + lr) * APAD + lk * 8);
            bf16x8 bl = *(const bf16x8*)(Xl + (fp * 16 + lr) * APAD + lk * 8);
            #pragma unroll
            for (int fo = 0; fo < 4; ++fo) {
                acc[fo][fp] = __builtin_amdgcn_mfma_f32_16x16x32_bf16(ah[fo], bh, acc[fo][fp], 0, 0, 0);
                acc[fo][fp] = __builtin_amdgcn_mfma_f32_16x16x32_bf16(al[fo], bh, acc[fo][fp], 0, 0, 0);
                acc[fo][fp] = __builtin_amdgcn_mfma_f32_16x16x32_bf16(ah[fo], bl, acc[fo][fp], 0, 0, 0);
            }
        }
    }

    // ---- fp32 epilogue: per-wave [32][68] float tile, 2 passes ----
    __syncthreads();
    float* Ef = (float*)lds + wid * (32 * 68);   // 4*32*68*4B = 34816 B <= 51200
    #pragma unroll
    for (int pass = 0; pass < 2; ++pass) {
        #pragma unroll
        for (int f2 = 0; f2 < 2; ++f2) {
            const int fo = pass * 2 + f2;
            #pragma unroll
            for (int fp = 0; fp < 4; ++fp)
                #pragma unroll
                for (int reg = 0; reg < 4; ++reg) {
                    const int o = o0 + wid * 64 + fo * 16 + lk * 4 + reg;
                    Ef[(f2 * 16 + lk * 4 + reg) * 68 + fp * 16 + lr] =
                        acc[fo][fp][reg] + bo[o];
                }
        }
        asm volatile("s_waitcnt lgkmcnt(0)" ::: "memory");
        __builtin_amdgcn_sched_barrier(0);
        #pragma unroll
        for (int it = 0; it < 8; ++it) {
            const int row = it * 4 + (lane >> 4);
            const int col = (lane & 15) * 4;
            float4 v = *(const float4*)&Ef[row * 68 + col];
            const int o = o0 + wid * 64 + pass * 32 + row;
            *(float4*)(outb + ((size_t)(b * 512 + o) * 16 + t) * 576 + p0 + col) = v;
        }
        asm volatile("s_waitcnt lgkmcnt(0)" ::: "memory");
        __builtin_amdgcn_sched_barrier(0);
    }
}

extern "C" void kernel_launch(void* const* d_in, const int* in_sizes, int n_in,
                              void* d_out, int out_size, void* d_ws, size_t ws_size,
                              hipStream_t stream)
{
    (void)in_sizes; (void)n_in; (void)out_size;
    const float* x   = (const float*)d_in[0];
    const float* wq  = (const float*)d_in[1];
    const float* bq  = (const float*)d_in[2];
    const float* wk  = (const float*)d_in[3];
    const float* bk  = (const float*)d_in[4];
    const float* wv  = (const float*)d_in[5];
    const float* bv  = (const float*)d_in[6];
    const float* wo  = (const float*)d_in[7];
    const float* bo  = (const float*)d_in[8];
    const float* pos = (const float*)d_in[9];

    ushort_t* xhi = (ushort_t*)d_ws;
    ushort_t* xlo = xhi + NXF;
    ushort_t* wsp = xlo + NXF;
    float* slab0 = (float*)(wsp + 8 * WELEM);
    const size_t head_bytes = (size_t)(2 * NXF + 8 * WELEM) * 2;

    const size_t per_bt = (size_t)3 * SLABF * sizeof(float);
    int chunk = 1;
    if (ws_size > head_bytes + per_bt) {
        size_t c = (ws_size - head_bytes) / per_bt;
        chunk = (c > 32) ? 32 : (int)c;
    }
    if (chunk < 1) chunk = 1;

    split_xT<<<dim3(9, 8, 32), 256, 0, stream>>>(x, pos, xhi, xlo);
    split_w<<<dim3(256, 4), 256, 0, stream>>>(wq, wk, wv, wo, wsp);

    for (int bt0 = 0; bt0 < 32; bt0 += chunk) {
        const int nbt = (32 - bt0 < chunk) ? (32 - bt0) : chunk;
        float* qslab = slab0;
        float* kslab = qslab + (size_t)nbt * SLABF;
        float* vslab = kslab + (size_t)nbt * SLABF;

        proj_qkv_mfma<<<dim3(nbt * 54), 256, 0, stream>>>(
            xhi, xlo, wsp, bq, bk, bv, qslab, kslab, vslab, bt0, nbt);
        attn_mfma<<<dim3(nbt * 72), 256, 0, stream>>>(qslab, kslab, vslab, nbt);
        proj_out_mfma<<<dim3(nbt * 18), 256, 0, stream>>>(
            qslab, wsp, bo, (float*)d_out, bt0, nbt);
    }
}

// Round 12
// 368.962 us; speedup vs baseline: 1.6073x; 1.6073x over previous
//
#include <hip/hip_runtime.h>
#include <math.h>

typedef unsigned short ushort_t;
typedef short bf16x8 __attribute__((ext_vector_type(8)));
typedef float f32x4 __attribute__((ext_vector_type(4)));

#define SLABF (512 * 576)     /* floats per (b,t) slab == ushorts per plane */
#define APAD  40              /* K-loop LDS row pad, halves (80 B) */
#define EPAD  72              /* epilogue LDS row pad, halves (144 B) */
#define NXF   (2 * 512 * 16 * 576)   /* elements per xT plane */
#define WELEM (512 * 512)
#define HPLANE (576 * 64)     /* per-head elements of [p][64] plane */

__device__ __forceinline__ float bf2f(ushort_t u) {
    union { unsigned int i; float f; } v;
    v.i = ((unsigned int)u) << 16;
    return v.f;
}
__device__ __forceinline__ ushort_t f2bf(float f) {
    union { float f; unsigned int i; } v;
    v.f = f;
    unsigned int r = v.i + 0x7FFFu + ((v.i >> 16) & 1u);
    return (ushort_t)(r >> 16);
}
__device__ __forceinline__ void split_hl(float x, ushort_t& hi, ushort_t& lo) {
    hi = f2bf(x);
    lo = f2bf(x - bf2f(hi));
}
__device__ __forceinline__ int xcd_swz(int L, int N) {
    return ((N & 7) == 0) ? ((L & 7) * (N >> 3) + (L >> 3)) : L;
}

// ---------------------------------------------------------------------------
// Prep 1: xT hi/lo planes of (x + pos), transposed to [bt][p=576][c=512].
// ---------------------------------------------------------------------------
__global__ __launch_bounds__(256)
void split_xT(const float* __restrict__ x, const float* __restrict__ pos,
              ushort_t* __restrict__ xhi, ushort_t* __restrict__ xlo)
{
    const int bt = blockIdx.z;
    const int b = bt >> 4, t = bt & 15;
    const int pt0 = blockIdx.x * 64;
    const int ct0 = blockIdx.y * 64;
    const int tid = threadIdx.x;

    __shared__ ushort_t Th[64][72], Tl[64][72];

    {
        const int cr = tid >> 2;
        const int pg = (tid & 3) * 16;
        const int c = ct0 + cr;
        const float pv = pos[c * 16 + t];
        const float* src = x + ((size_t)(b * 512 + c) * 16 + t) * 576 + pt0 + pg;
        #pragma unroll
        for (int jj = 0; jj < 4; ++jj) {
            float4 v = *(const float4*)(src + jj * 4);
            v.x += pv; v.y += pv; v.z += pv; v.w += pv;
            ushort_t h, l;
            split_hl(v.x, h, l); Th[pg + jj*4 + 0][cr] = h; Tl[pg + jj*4 + 0][cr] = l;
            split_hl(v.y, h, l); Th[pg + jj*4 + 1][cr] = h; Tl[pg + jj*4 + 1][cr] = l;
            split_hl(v.z, h, l); Th[pg + jj*4 + 2][cr] = h; Tl[pg + jj*4 + 2][cr] = l;
            split_hl(v.w, h, l); Th[pg + jj*4 + 3][cr] = h; Tl[pg + jj*4 + 3][cr] = l;
        }
    }
    __syncthreads();
    {
        const int pr = tid >> 2;
        const int cg = (tid & 3) * 16;
        const size_t obase = (size_t)bt * (576 * 512) + (size_t)(pt0 + pr) * 512 + ct0 + cg;
        #pragma unroll
        for (int m = 0; m < 2; ++m) {
            *(uint4*)(xhi + obase + m * 8) = *(const uint4*)&Th[pr][cg + m * 8];
            *(uint4*)(xlo + obase + m * 8) = *(const uint4*)&Tl[pr][cg + m * 8];
        }
    }
}

// ---------------------------------------------------------------------------
// Prep 2: weight hi/lo planes.
// ---------------------------------------------------------------------------
__global__ __launch_bounds__(256)
void split_w(const float* __restrict__ w0, const float* __restrict__ w1,
             const float* __restrict__ w2, const float* __restrict__ w3,
             ushort_t* __restrict__ wsp)
{
    const int m = blockIdx.y;
    const float* W = (m == 0) ? w0 : (m == 1) ? w1 : (m == 2) ? w2 : w3;
    ushort_t* hi = wsp + (size_t)m * 2 * WELEM;
    ushort_t* lo = hi + WELEM;
    const int idx = blockIdx.x * 256 + threadIdx.x;
    float4 v = ((const float4*)W)[idx];
    ushort4 h, l;
    split_hl(v.x, h.x, l.x);
    split_hl(v.y, h.y, l.y);
    split_hl(v.z, h.z, l.z);
    split_hl(v.w, h.w, l.w);
    ((ushort4*)hi)[idx] = h;
    ((ushort4*)lo)[idx] = l;
}

// ---------------------------------------------------------------------------
// QKV projection, MFMA hi/lo 3-pass, 256o x 64p tile, BK=32, 4 waves.
// K-loop: round-8 structure (direct global->LDS staging, no reg prefetch —
// proven 96-VGPR no-spill). Epilogue: per-wave LDS transpose tile ->
// full-line uint4 stores (each 128B line fully dirty in ONE instruction).
// Outputs: Q planes [h][p][64] (pre-scaled 0.125), K planes [h][kv][64],
//          V planes [h][d][576]; all hi/lo.
// ---------------------------------------------------------------------------
__global__ __launch_bounds__(256)
void proj_qkv_mfma(const ushort_t* __restrict__ xhi, const ushort_t* __restrict__ xlo,
                   const ushort_t* __restrict__ wsp,
                   const float* __restrict__ bq, const float* __restrict__ bk,
                   const float* __restrict__ bv,
                   float* __restrict__ qs, float* __restrict__ ks, float* __restrict__ vs,
                   int bt_base, int nbt)
{
    const int w = xcd_swz(blockIdx.x, nbt * 54);
    const int btl = w / 54;
    int r = w - btl * 54;
    const int mode = r / 18; r -= mode * 18;
    const int ot = r / 9;
    const int pt = r - ot * 9;
    const int bt = bt_base + btl;

    const ushort_t* Whi = wsp + (size_t)mode * (2 * WELEM);
    const ushort_t* Wlo = Whi + WELEM;
    const float* bias = (mode == 0) ? bq : (mode == 1) ? bk : bv;
    float* outf = ((mode == 0) ? qs : (mode == 1) ? ks : vs) + (size_t)btl * SLABF;
    ushort_t* ohi = (ushort_t*)outf;
    ushort_t* olo = ohi + SLABF;

    const int o0 = ot * 256;
    const int p0 = pt * 64;
    const int tid = threadIdx.x;
    const int wid = tid >> 6;
    const int lane = tid & 63;
    const int lr = lane & 15;
    const int lk = lane >> 4;

    __shared__ __align__(16) ushort_t lds[25600];   // 51200 B, reused by epilogue
    ushort_t* Wh = lds;                 // 256*APAD
    ushort_t* Wl = lds + 10240;
    ushort_t* Xh = lds + 20480;         // 64*APAD
    ushort_t* Xl = lds + 23040;

    f32x4 acc[4][4];
    #pragma unroll
    for (int i = 0; i < 4; ++i)
        #pragma unroll
        for (int j = 0; j < 4; ++j) { f32x4 zz = {0.f,0.f,0.f,0.f}; acc[i][j] = zz; }

    const int brow = tid >> 2, boff = (tid & 3) * 8;
    const ushort_t* xbh = xhi + (size_t)bt * (576 * 512);
    const ushort_t* xbl = xlo + (size_t)bt * (576 * 512);

    for (int c0 = 0; c0 < 512; c0 += 32) {
        #pragma unroll
        for (int k = 0; k < 4; ++k) {
            const int ci = tid + k * 256;
            const int row = ci >> 2, off = (ci & 3) * 8;
            const size_t g = (size_t)(o0 + row) * 512 + c0 + off;
            *(bf16x8*)(Wh + row * APAD + off) = *(const bf16x8*)(Whi + g);
            *(bf16x8*)(Wl + row * APAD + off) = *(const bf16x8*)(Wlo + g);
        }
        {
            const size_t g = (size_t)(p0 + brow) * 512 + c0 + boff;
            *(bf16x8*)(Xh + brow * APAD + boff) = *(const bf16x8*)(xbh + g);
            *(bf16x8*)(Xl + brow * APAD + boff) = *(const bf16x8*)(xbl + g);
        }
        __syncthreads();

        bf16x8 ah[4], al[4];
        #pragma unroll
        for (int fo = 0; fo < 4; ++fo) {
            ah[fo] = *(const bf16x8*)(Wh + (wid * 64 + fo * 16 + lr) * APAD + lk * 8);
            al[fo] = *(const bf16x8*)(Wl + (wid * 64 + fo * 16 + lr) * APAD + lk * 8);
        }
        #pragma unroll
        for (int fp = 0; fp < 4; ++fp) {
            bf16x8 bh = *(const bf16x8*)(Xh + (fp * 16 + lr) * APAD + lk * 8);
            bf16x8 bl = *(const bf16x8*)(Xl + (fp * 16 + lr) * APAD + lk * 8);
            #pragma unroll
            for (int fo = 0; fo < 4; ++fo) {
                acc[fo][fp] = __builtin_amdgcn_mfma_f32_16x16x32_bf16(ah[fo], bh, acc[fo][fp], 0, 0, 0);
                acc[fo][fp] = __builtin_amdgcn_mfma_f32_16x16x32_bf16(al[fo], bh, acc[fo][fp], 0, 0, 0);
                acc[fo][fp] = __builtin_amdgcn_mfma_f32_16x16x32_bf16(ah[fo], bl, acc[fo][fp], 0, 0, 0);
            }
        }
        __syncthreads();
    }

    // ---- epilogue: per-wave LDS tile [64][EPAD], 2 passes (hi, lo) ----
    // (K-loop ends with a barrier, so LDS reuse is safe.)
    ushort_t* Ew = lds + wid * (64 * EPAD);   // 4*64*72 = 18432 halves <= 25600
    const int head = (o0 >> 6) + wid;

    #pragma unroll
    for (int pass = 0; pass < 2; ++pass) {
        if (mode != 2) {
            // Q/K tile rows = p', cols = d' (ushort4 staging: 4 consec d')
            #pragma unroll
            for (int fo = 0; fo < 4; ++fo)
                #pragma unroll
                for (int fp = 0; fp < 4; ++fp) {
                    ushort4 s;
                    #pragma unroll
                    for (int reg = 0; reg < 4; ++reg) {
                        const int o = o0 + wid * 64 + fo * 16 + lk * 4 + reg;
                        float v = acc[fo][fp][reg] + bias[o];
                        if (mode == 0) v *= 0.125f;
                        ushort_t hi = f2bf(v);
                        ((ushort_t*)&s)[reg] = pass ? f2bf(v - bf2f(hi)) : hi;
                    }
                    *(ushort4*)&Ew[(fp * 16 + lr) * EPAD + fo * 16 + lk * 4] = s;
                }
        } else {
            // V tile rows = d', cols = p'
            #pragma unroll
            for (int fo = 0; fo < 4; ++fo)
                #pragma unroll
                for (int fp = 0; fp < 4; ++fp)
                    #pragma unroll
                    for (int reg = 0; reg < 4; ++reg) {
                        const int o = o0 + wid * 64 + fo * 16 + lk * 4 + reg;
                        float v = acc[fo][fp][reg] + bias[o];
                        ushort_t hi = f2bf(v);
                        Ew[(fo * 16 + lk * 4 + reg) * EPAD + fp * 16 + lr] =
                            pass ? f2bf(v - bf2f(hi)) : hi;
                    }
        }
        asm volatile("s_waitcnt lgkmcnt(0)" ::: "memory");
        __builtin_amdgcn_sched_barrier(0);

        ushort_t* dst = pass ? olo : ohi;
        #pragma unroll
        for (int it = 0; it < 8; ++it) {
            const int row = it * 8 + (lane >> 3);
            const int off = (lane & 7) * 8;
            uint4 v = *(const uint4*)&Ew[row * EPAD + off];
            if (mode != 2)
                *(uint4*)(dst + (size_t)head * HPLANE + (size_t)(p0 + row) * 64 + off) = v;
            else
                *(uint4*)(dst + (size_t)(o0 + wid * 64 + row) * 576 + p0 + off) = v;
        }
        asm volatile("s_waitcnt lgkmcnt(0)" ::: "memory");   // ds_reads retire before pass-1 overwrite
        __builtin_amdgcn_sched_barrier(0);
    }
}

// ---------------------------------------------------------------------------
// Attention via MFMA, hi/lo 3-pass — byte-identical to the 428 us run.
// ---------------------------------------------------------------------------
__global__ __launch_bounds__(256)
void attn_mfma(float* __restrict__ qs, const float* __restrict__ ks,
               const float* __restrict__ vs, int nbt)
{
    const int w9 = xcd_swz(blockIdx.x, nbt * 72);
    const int pair = w9 / 9;
    const int qt = w9 - pair * 9;
    const int btl = pair >> 3;
    const int h = pair & 7;

    const int tid = threadIdx.x;
    const int wid = tid >> 6;
    const int lane = tid & 63;
    const int lr = lane & 15;
    const int lk = lane >> 4;

    const size_t slab = (size_t)btl * SLABF;
    ushort_t* Qhi_g = (ushort_t*)(qs + slab) + (size_t)h * HPLANE;
    ushort_t* Qlo_g = (ushort_t*)(qs + slab) + SLABF + (size_t)h * HPLANE;
    const ushort_t* kbase = (const ushort_t*)(ks + slab);
    const ushort_t* Khi_g = kbase + (size_t)h * HPLANE;
    const ushort_t* Klo_g = kbase + SLABF + (size_t)h * HPLANE;
    const ushort_t* vbase = (const ushort_t*)(vs + slab);
    const ushort_t* Vhi_g = vbase + (size_t)h * HPLANE;
    const ushort_t* Vlo_g = vbase + SLABF + (size_t)h * HPLANE;

    __shared__ ushort_t Kh[32][72], Kl[32][72];
    __shared__ ushort_t Vh[64][40], Vl[64][40];
    __shared__ ushort_t Qh[64][72], Ql[64][72];
    __shared__ ushort_t Ph[4][16][40], Pl[4][16][40];
    __shared__ float Lrow[4][16];

    #pragma unroll
    for (int k = 0; k < 2; ++k) {
        const int ci = tid + k * 256;
        const int row = ci >> 3;
        const int off = (ci & 7) * 8;
        const size_t g = (size_t)(qt * 64 + row) * 64 + off;
        *(uint4*)&Qh[row][off] = *(const uint4*)(Qhi_g + g);
        *(uint4*)&Ql[row][off] = *(const uint4*)(Qlo_g + g);
    }

    const int skv = tid >> 3, sd = (tid & 7) * 8;
    const int svd = tid >> 2, skb = (tid & 3) * 8;
    uint4 kh_r, kl_r, vh_r, vl_r;

    {
        const size_t ko = (size_t)skv * 64 + sd;
        kh_r = *(const uint4*)(Khi_g + ko);
        kl_r = *(const uint4*)(Klo_g + ko);
        const size_t vo = (size_t)svd * 576 + skb;
        vh_r = *(const uint4*)(Vhi_g + vo);
        vl_r = *(const uint4*)(Vlo_g + vo);
        *(uint4*)&Kh[skv][sd] = kh_r; *(uint4*)&Kl[skv][sd] = kl_r;
        *(uint4*)&Vh[svd][skb] = vh_r; *(uint4*)&Vl[svd][skb] = vl_r;
    }
    __syncthreads();

    bf16x8 qh0 = *(const bf16x8*)&Qh[wid * 16 + lr][lk * 8];
    bf16x8 ql0 = *(const bf16x8*)&Ql[wid * 16 + lr][lk * 8];
    bf16x8 qh1 = *(const bf16x8*)&Qh[wid * 16 + lr][32 + lk * 8];
    bf16x8 ql1 = *(const bf16x8*)&Ql[wid * 16 + lr][32 + lk * 8];

    f32x4 o[4];
    #pragma unroll
    for (int nf = 0; nf < 4; ++nf) { f32x4 zz = {0.f,0.f,0.f,0.f}; o[nf] = zz; }
    float lsum = 0.f;

    const int NT = 18;
    for (int tt = 0; tt < NT; ++tt) {
        if (tt + 1 < NT) {
            const size_t ko = (size_t)((tt + 1) * 32 + skv) * 64 + sd;
            kh_r = *(const uint4*)(Khi_g + ko);
            kl_r = *(const uint4*)(Klo_g + ko);
            const size_t vo = (size_t)svd * 576 + (tt + 1) * 32 + skb;
            vh_r = *(const uint4*)(Vhi_g + vo);
            vl_r = *(const uint4*)(Vlo_g + vo);
        }

        f32x4 s0 = {0.f,0.f,0.f,0.f}, s1 = {0.f,0.f,0.f,0.f};
        #pragma unroll
        for (int ks2 = 0; ks2 < 2; ++ks2) {
            const int dof = ks2 * 32 + lk * 8;
            bf16x8 qh = ks2 ? qh1 : qh0;
            bf16x8 ql = ks2 ? ql1 : ql0;
            bf16x8 k0h = *(const bf16x8*)&Kh[lr][dof];
            bf16x8 k0l = *(const bf16x8*)&Kl[lr][dof];
            bf16x8 k1h = *(const bf16x8*)&Kh[16 + lr][dof];
            bf16x8 k1l = *(const bf16x8*)&Kl[16 + lr][dof];
            s0 = __builtin_amdgcn_mfma_f32_16x16x32_bf16(k0h, qh, s0, 0, 0, 0);
            s0 = __builtin_amdgcn_mfma_f32_16x16x32_bf16(k0l, qh, s0, 0, 0, 0);
            s0 = __builtin_amdgcn_mfma_f32_16x16x32_bf16(k0h, ql, s0, 0, 0, 0);
            s1 = __builtin_amdgcn_mfma_f32_16x16x32_bf16(k1h, qh, s1, 0, 0, 0);
            s1 = __builtin_amdgcn_mfma_f32_16x16x32_bf16(k1l, qh, s1, 0, 0, 0);
            s1 = __builtin_amdgcn_mfma_f32_16x16x32_bf16(k1h, ql, s1, 0, 0, 0);
        }

        #pragma unroll
        for (int f = 0; f < 2; ++f) {
            f32x4 sv = f ? s1 : s0;
            float p0 = __expf(sv[0]);
            float p1 = __expf(sv[1]);
            float p2 = __expf(sv[2]);
            float p3 = __expf(sv[3]);
            lsum += (p0 + p1) + (p2 + p3);
            ushort_t h0, l0, h1, l1, h2, l2, h3, l3;
            split_hl(p0, h0, l0); split_hl(p1, h1, l1);
            split_hl(p2, h2, l2); split_hl(p3, h3, l3);
            uint2 wh, wl;
            wh.x = (unsigned int)h0 | ((unsigned int)h1 << 16);
            wh.y = (unsigned int)h2 | ((unsigned int)h3 << 16);
            wl.x = (unsigned int)l0 | ((unsigned int)l1 << 16);
            wl.y = (unsigned int)l2 | ((unsigned int)l3 << 16);
            *(uint2*)&Ph[wid][lr][f * 16 + lk * 4] = wh;
            *(uint2*)&Pl[wid][lr][f * 16 + lk * 4] = wl;
        }
        asm volatile("s_waitcnt lgkmcnt(0)" ::: "memory");
        __builtin_amdgcn_sched_barrier(0);

        {
            bf16x8 pah = *(const bf16x8*)&Ph[wid][lr][lk * 8];
            bf16x8 pal = *(const bf16x8*)&Pl[wid][lr][lk * 8];
            #pragma unroll
            for (int nf = 0; nf < 4; ++nf) {
                bf16x8 vhf = *(const bf16x8*)&Vh[nf * 16 + lr][lk * 8];
                bf16x8 vlf = *(const bf16x8*)&Vl[nf * 16 + lr][lk * 8];
                o[nf] = __builtin_amdgcn_mfma_f32_16x16x32_bf16(pah, vhf, o[nf], 0, 0, 0);
                o[nf] = __builtin_amdgcn_mfma_f32_16x16x32_bf16(pal, vhf, o[nf], 0, 0, 0);
                o[nf] = __builtin_amdgcn_mfma_f32_16x16x32_bf16(pah, vlf, o[nf], 0, 0, 0);
            }
        }

        __syncthreads();
        if (tt + 1 < NT) {
            *(uint4*)&Kh[skv][sd] = kh_r; *(uint4*)&Kl[skv][sd] = kl_r;
            *(uint4*)&Vh[svd][skb] = vh_r; *(uint4*)&Vl[svd][skb] = vl_r;
            __syncthreads();
        }
    }

    lsum += __shfl_xor(lsum, 16);
    lsum += __shfl_xor(lsum, 32);
    if (lk == 0) Lrow[wid][lr] = lsum;
    asm volatile("s_waitcnt lgkmcnt(0)" ::: "memory");
    __builtin_amdgcn_sched_barrier(0);

    float4 lv = *(float4*)&Lrow[wid][lk * 4];
    const float inv[4] = {1.f / lv.x, 1.f / lv.y, 1.f / lv.z, 1.f / lv.w};

    // ---- AO in place into Q planes [h][p][64] (428-run layout/stores) ----
    const int qrow = qt * 64 + wid * 16 + lk * 4;
    #pragma unroll
    for (int nf = 0; nf < 4; ++nf)
        #pragma unroll
        for (int reg = 0; reg < 4; ++reg) {
            float v = o[nf][reg] * inv[reg];
            ushort_t hi, lo; split_hl(v, hi, lo);
            const size_t off = (size_t)(qrow + reg) * 64 + nf * 16 + lr;
            Qhi_g[off] = hi; Qlo_g[off] = lo;
        }
}

// ---------------------------------------------------------------------------
// Output projection, MFMA hi/lo 3-pass — byte-identical to the 428 us run.
// ---------------------------------------------------------------------------
__global__ __launch_bounds__(256)
void proj_out_mfma(const float* __restrict__ ao, const ushort_t* __restrict__ wsp,
                   const float* __restrict__ bo, float* __restrict__ outb,
                   int bt_base, int nbt)
{
    const int w = xcd_swz(blockIdx.x, nbt * 18);
    const int btl = w / 18;
    int r = w - btl * 18;
    const int ot = r / 9;
    const int pt = r - ot * 9;
    const int bt = bt_base + btl;
    const int b = bt >> 4, t = bt & 15;

    const ushort_t* AOhi = (const ushort_t*)(ao + (size_t)btl * SLABF);
    const ushort_t* AOlo = AOhi + SLABF;
    const ushort_t* Whi = wsp + (size_t)3 * (2 * WELEM);
    const ushort_t* Wlo = Whi + WELEM;

    const int o0 = ot * 256;
    const int p0 = pt * 64;
    const int tid = threadIdx.x;
    const int wid = tid >> 6;
    const int lane = tid & 63;
    const int lr = lane & 15;
    const int lk = lane >> 4;

    __shared__ ushort_t Wh[256 * APAD], Wl[256 * APAD];
    __shared__ ushort_t Xh[64 * APAD],  Xl[64 * APAD];

    f32x4 acc[4][4];
    #pragma unroll
    for (int i = 0; i < 4; ++i)
        #pragma unroll
        for (int j = 0; j < 4; ++j) { f32x4 zz = {0.f,0.f,0.f,0.f}; acc[i][j] = zz; }

    const int brow = tid >> 2, boff = (tid & 3) * 8;

    for (int c0 = 0; c0 < 512; c0 += 32) {
        #pragma unroll
        for (int k = 0; k < 4; ++k) {
            const int ci = tid + k * 256;
            const int row = ci >> 2, off = (ci & 3) * 8;
            const size_t g = (size_t)(o0 + row) * 512 + c0 + off;
            *(bf16x8*)(Wh + row * APAD + off) = *(const bf16x8*)(Whi + g);
            *(bf16x8*)(Wl + row * APAD + off) = *(const bf16x8*)(Wlo + g);
        }
        {
            // AO row for c-range [c0, c0+32): head h=c0>>6, d0 = c0&63
            const size_t g = (size_t)(c0 >> 6) * HPLANE
                           + (size_t)(p0 + brow) * 64 + (c0 & 63) + boff;
            *(bf16x8*)(Xh + brow * APAD + boff) = *(const bf16x8*)(AOhi + g);
            *(bf16x8*)(Xl + brow * APAD + boff) = *(const bf16x8*)(AOlo + g);
        }
        __syncthreads();

        bf16x8 ah[4], al[4];
        #pragma unroll
        for (int fo = 0; fo < 4; ++fo) {
            ah[fo] = *(const bf16x8*)(Wh + (wid * 64 + fo * 16 + lr) * APAD + lk * 8);
            al[fo] = *(const bf16x8*)(Wl + (wid * 64 + fo * 16 + lr) * APAD + lk * 8);
        }
        #pragma unroll
        for (int fp = 0; fp < 4; ++fp) {
            bf16x8 bh = *(const bf16x8*)(Xh + (fp * 16 + lr) * APAD + lk * 8);
            bf16x8 bl = *(const bf16x8*)(Xl + (fp * 16 + lr) * APAD + lk * 8);
            #pragma unroll
            for (int fo = 0; fo < 4; ++fo) {
                acc[fo][fp] = __builtin_amdgcn_mfma_f32_16x16x32_bf16(ah[fo], bh, acc[fo][fp], 0, 0, 0);
                acc[fo][fp] = __builtin_amdgcn_mfma_f32_16x16x32_bf16(al[fo], bh, acc[fo][fp], 0, 0, 0);
                acc[fo][fp] = __builtin_amdgcn_mfma_f32_16x16x32_bf16(ah[fo], bl, acc[fo][fp], 0, 0, 0);
            }
        }
        __syncthreads();
    }

    #pragma unroll
    for (int fo = 0; fo < 4; ++fo)
        #pragma unroll
        for (int reg = 0; reg < 4; ++reg) {
            const int o = o0 + wid * 64 + fo * 16 + lk * 4 + reg;
            const float bb = bo[o];
            const size_t base = ((size_t)(b * 512 + o) * 16 + t) * 576;
            #pragma unroll
            for (int fp = 0; fp < 4; ++fp)
                outb[base + p0 + fp * 16 + lr] = acc[fo][fp][reg] + bb;
        }
}

extern "C" void kernel_launch(void* const* d_in, const int* in_sizes, int n_in,
                              void* d_out, int out_size, void* d_ws, size_t ws_size,
                              hipStream_t stream)
{
    (void)in_sizes; (void)n_in; (void)out_size;
    const float* x   = (const float*)d_in[0];
    const float* wq  = (const float*)d_in[1];
    const float* bq  = (const float*)d_in[2];
    const float* wk  = (const float*)d_in[3];
    const float* bk  = (const float*)d_in[4];
    const float* wv  = (const float*)d_in[5];
    const float* bv  = (const float*)d_in[6];
    const float* wo  = (const float*)d_in[7];
    const float* bo  = (const float*)d_in[8];
    const float* pos = (const float*)d_in[9];

    ushort_t* xhi = (ushort_t*)d_ws;
    ushort_t* xlo = xhi + NXF;
    ushort_t* wsp = xlo + NXF;
    float* slab0 = (float*)(wsp + 8 * WELEM);
    const size_t head_bytes = (size_t)(2 * NXF + 8 * WELEM) * 2;

    const size_t per_bt = (size_t)3 * SLABF * sizeof(float);
    int chunk = 1;
    if (ws_size > head_bytes + per_bt) {
        size_t c = (ws_size - head_bytes) / per_bt;
        chunk = (c > 32) ? 32 : (int)c;
    }
    if (chunk < 1) chunk = 1;

    split_xT<<<dim3(9, 8, 32), 256, 0, stream>>>(x, pos, xhi, xlo);
    split_w<<<dim3(256, 4), 256, 0, stream>>>(wq, wk, wv, wo, wsp);

    for (int bt0 = 0; bt0 < 32; bt0 += chunk) {
        const int nbt = (32 - bt0 < chunk) ? (32 - bt0) : chunk;
        float* qslab = slab0;
        float* kslab = qslab + (size_t)nbt * SLABF;
        float* vslab = kslab + (size_t)nbt * SLABF;

        proj_qkv_mfma<<<dim3(nbt * 54), 256, 0, stream>>>(
            xhi, xlo, wsp, bq, bk, bv, qslab, kslab, vslab, bt0, nbt);
        attn_mfma<<<dim3(nbt * 72), 256, 0, stream>>>(qslab, kslab, vslab, nbt);
        proj_out_mfma<<<dim3(nbt * 18), 256, 0, stream>>>(
            qslab, wsp, bo, (float*)d_out, bt0, nbt);
    }
}